// Round 2
// baseline (18698.532 us; speedup 1.0000x reference)
//
#include <hip/hip_runtime.h>
#include <math.h>

static constexpr int H = 256, W = 256, HW = H * W;

// ---------- activations ----------
__device__ __forceinline__ float gelu_f(float v) {
  return 0.5f * v * (1.0f + erff(v * 0.70710678118654752440f));
}

template<int ACT>
__device__ __forceinline__ float apply_act(float v) {
  if constexpr (ACT == 1) return v >= 0.f ? v : 0.1f * v;   // LeakyReLU(0.1)
  if constexpr (ACT == 2) return gelu_f(v);
  return v;
}

// ---------- 3x3 same-pad conv, NCHW, f32, weights+inputs staged in LDS ----------
// Tile: 64 wide x TH tall. 256 threads as 16x16: tx=col-group (4 cols), ty=row-group
// (RT=TH/16 rows). OCPB output channels per block. Input channels in chunks of 4.
// Inner loop is pure VALU FMA + LDS reads (b128 input rows, broadcast weights).
template<int CIN, int OCPB, int TH, int ACT>
__global__ __launch_bounds__(256, 4)
void conv3x3_k(const float* __restrict__ in0, const float* __restrict__ in1, int cin0,
               const float* __restrict__ w, const float* __restrict__ bias,
               float* __restrict__ out, int ocTotal)
{
  constexpr int CCH = 4;
  constexpr int RT  = TH / 16;          // output rows per thread
  constexpr int IR  = TH + 2;           // staged input rows (halo)
  constexpr int ICOL = 66, ISTR = 68;   // valid cols, padded row stride (16B-aligned)
  __shared__ __align__(16) float sIn[CCH][IR][ISTR];
  __shared__ __align__(16) float sW[CCH][OCPB][12];

  const int tx = threadIdx.x & 15;
  const int ty = threadIdx.x >> 4;
  const int x0 = blockIdx.x * 64;
  const int y0 = blockIdx.y * TH;
  const int nOcC = ocTotal / OCPB;
  const int b   = blockIdx.z / nOcC;
  const int oc0 = (blockIdx.z % nOcC) * OCPB;

  float acc[OCPB][RT][4];
  #pragma unroll
  for (int o = 0; o < OCPB; ++o) {
    float bv = bias ? bias[oc0 + o] : 0.f;
    #pragma unroll
    for (int r = 0; r < RT; ++r)
      #pragma unroll
      for (int j = 0; j < 4; ++j) acc[o][r][j] = bv;
  }

  #pragma unroll 1
  for (int cc = 0; cc < CIN; cc += CCH) {
    __syncthreads();
    // ---- stage input chunk (with halo, zero-padded at borders) ----
    for (int t = threadIdx.x; t < CCH * IR * ICOL; t += 256) {
      int c   = t / (IR * ICOL);
      int rem = t - c * (IR * ICOL);
      int r   = rem / ICOL;
      int col = rem - r * ICOL;
      int gy = y0 + r - 1, gx = x0 + col - 1;
      int ci = cc + c;
      float v = 0.f;
      if (gy >= 0 && gy < H && gx >= 0 && gx < W) {
        if (ci < cin0) v = in0[(((size_t)b * cin0 + ci) * H + gy) * W + gx];
        else           v = in1[(((size_t)b * (CIN - cin0) + (ci - cin0)) * H + gy) * W + gx];
      }
      sIn[c][r][col] = v;
    }
    // ---- stage weight chunk ----
    for (int t = threadIdx.x; t < CCH * OCPB * 9; t += 256) {
      int c   = t / (OCPB * 9);
      int rem = t - c * (OCPB * 9);
      int o   = rem / 9;
      int k   = rem - o * 9;
      sW[c][o][k] = w[((size_t)(oc0 + o) * CIN + cc + c) * 9 + k];
    }
    __syncthreads();

    #pragma unroll
    for (int c = 0; c < CCH; ++c) {
      float iv[RT + 2][6];
      #pragma unroll
      for (int r = 0; r < RT + 2; ++r) {
        const float* rp = &sIn[c][ty * RT + r][tx * 4];
        float4 a = *(const float4*)rp;
        float2 bq = *(const float2*)(rp + 4);
        iv[r][0] = a.x; iv[r][1] = a.y; iv[r][2] = a.z; iv[r][3] = a.w;
        iv[r][4] = bq.x; iv[r][5] = bq.y;
      }
      #pragma unroll
      for (int o = 0; o < OCPB; ++o) {
        const float4 wa = *(const float4*)&sW[c][o][0];
        const float4 wb = *(const float4*)&sW[c][o][4];
        const float  w8 = sW[c][o][8];
        #pragma unroll
        for (int r = 0; r < RT; ++r) {
          #pragma unroll
          for (int j = 0; j < 4; ++j) {
            acc[o][r][j] += iv[r + 0][j + 0] * wa.x + iv[r + 0][j + 1] * wa.y + iv[r + 0][j + 2] * wa.z
                          + iv[r + 1][j + 0] * wa.w + iv[r + 1][j + 1] * wb.x + iv[r + 1][j + 2] * wb.y
                          + iv[r + 2][j + 0] * wb.z + iv[r + 2][j + 1] * wb.w + iv[r + 2][j + 2] * w8;
          }
        }
      }
    }
  }

  #pragma unroll
  for (int o = 0; o < OCPB; ++o) {
    #pragma unroll
    for (int r = 0; r < RT; ++r) {
      int oy = y0 + ty * RT + r;
      float4 v;
      v.x = apply_act<ACT>(acc[o][r][0]);
      v.y = apply_act<ACT>(acc[o][r][1]);
      v.z = apply_act<ACT>(acc[o][r][2]);
      v.w = apply_act<ACT>(acc[o][r][3]);
      *(float4*)&out[(((size_t)b * ocTotal + oc0 + o) * H + oy) * W + x0 + tx * 4] = v;
    }
  }
}

// ---------- 1x1 conv, NCHW, f32, weights in LDS, 4 px/thread ----------
template<int CIN, int OCPB, int ACT>
__global__ __launch_bounds__(256, 4)
void conv1x1_k(const float* __restrict__ in, const float* __restrict__ w,
               float* __restrict__ out, int ocTotal)
{
  __shared__ __align__(16) float sW[OCPB][CIN];
  const int b   = blockIdx.y;
  const int oc0 = blockIdx.z * OCPB;
  for (int t = threadIdx.x; t < OCPB * CIN; t += 256)
    sW[t / CIN][t % CIN] = w[(size_t)(oc0 + t / CIN) * CIN + (t % CIN)];
  __syncthreads();

  const int p4 = (blockIdx.x * 256 + threadIdx.x) * 4;
  const float* ip = in + (size_t)b * CIN * HW + p4;
  float acc[OCPB][4];
  #pragma unroll
  for (int o = 0; o < OCPB; ++o)
    #pragma unroll
    for (int j = 0; j < 4; ++j) acc[o][j] = 0.f;

  #pragma unroll 2
  for (int ci = 0; ci < CIN; ci += 4) {
    float4 v0 = *(const float4*)(ip + (size_t)(ci + 0) * HW);
    float4 v1 = *(const float4*)(ip + (size_t)(ci + 1) * HW);
    float4 v2 = *(const float4*)(ip + (size_t)(ci + 2) * HW);
    float4 v3 = *(const float4*)(ip + (size_t)(ci + 3) * HW);
    #pragma unroll
    for (int o = 0; o < OCPB; ++o) {
      const float4 wv = *(const float4*)&sW[o][ci];
      acc[o][0] += v0.x * wv.x + v1.x * wv.y + v2.x * wv.z + v3.x * wv.w;
      acc[o][1] += v0.y * wv.x + v1.y * wv.y + v2.y * wv.z + v3.y * wv.w;
      acc[o][2] += v0.z * wv.x + v1.z * wv.y + v2.z * wv.z + v3.z * wv.w;
      acc[o][3] += v0.w * wv.x + v1.w * wv.y + v2.w * wv.z + v3.w * wv.w;
    }
  }
  #pragma unroll
  for (int o = 0; o < OCPB; ++o) {
    float4 v;
    v.x = apply_act<ACT>(acc[o][0]);
    v.y = apply_act<ACT>(acc[o][1]);
    v.z = apply_act<ACT>(acc[o][2]);
    v.w = apply_act<ACT>(acc[o][3]);
    *(float4*)&out[((size_t)b * ocTotal + oc0 + o) * HW + p4] = v;
  }
}

// ---------- corr (einsum) + top-3 (jax tie-break: lower index wins) ----------
__global__ __launch_bounds__(256)
void corr_topk_k(const float* __restrict__ warp, const float* __restrict__ x,
                 int* __restrict__ idxo)
{
  const int p = blockIdx.x * 256 + threadIdx.x;
  const int b = blockIdx.y;
  float corr[9];
  #pragma unroll
  for (int o = 0; o < 9; ++o) corr[o] = 0.f;
  #pragma unroll 2
  for (int c = 0; c < 32; ++c) {
    float xv = x[((size_t)b * 32 + c) * HW + p];
    const float* wp = warp + ((size_t)b * 288 + (size_t)c * 9) * HW + p;
    #pragma unroll
    for (int o = 0; o < 9; ++o) corr[o] += wp[(size_t)o * HW] * xv;
  }
  unsigned mask = 0;
  int packed = 0;
  #pragma unroll
  for (int t = 0; t < 3; ++t) {
    float best = -INFINITY; int bi = 0;
    #pragma unroll
    for (int o = 0; o < 9; ++o) {
      bool take = (((mask >> o) & 1u) == 0u) && (corr[o] > best);
      best = take ? corr[o] : best;
      bi   = take ? o       : bi;
    }
    mask   |= 1u << bi;
    packed |= bi << (4 * t);
  }
  idxo[(size_t)b * HW + p] = packed;
}

// ---------- gather selected warps + 3x3 conv with w_sel ----------
__global__ __launch_bounds__(256)
void selconv_k(const float* __restrict__ warp, const int* __restrict__ idxp,
               const float* __restrict__ wsel, const float* __restrict__ bsel,
               float* __restrict__ out)
{
  const int tx = threadIdx.x & 31, ty = threadIdx.x >> 5;
  const int px = blockIdx.x * 32 + tx;
  const int py = blockIdx.y * 8 + ty;
  const int b  = blockIdx.z;

  int  nidx[9];
  bool nval[9];
  int  qoff[9];
  #pragma unroll
  for (int kh = 0; kh < 3; ++kh)
    #pragma unroll
    for (int kw = 0; kw < 3; ++kw) {
      int k = kh * 3 + kw;
      int qy = py + kh - 1, qx = px + kw - 1;
      nval[k] = (qy >= 0 && qy < H && qx >= 0 && qx < W);
      qoff[k] = qy * W + qx;
      nidx[k] = nval[k] ? idxp[(size_t)b * HW + qoff[k]] : 0;
    }

  float ws27[27];
  #pragma unroll
  for (int i = 0; i < 27; ++i) ws27[i] = wsel[i];
  const float bs = bsel[0];

  #pragma unroll 1
  for (int c = 0; c < 32; ++c) {
    float acc = bs;
    const float* wb = warp + ((size_t)b * 288 + (size_t)c * 9) * HW;
    #pragma unroll
    for (int k = 0; k < 9; ++k) {
      if (nval[k]) {
        int pk = nidx[k];
        #pragma unroll
        for (int t = 0; t < 3; ++t) {
          int o = (pk >> (4 * t)) & 15;
          acc += ws27[t * 9 + k] * wb[(size_t)o * HW + qoff[k]];
        }
      }
    }
    out[((size_t)b * 32 + c) * HW + (size_t)py * W + px] = acc;
  }
}

// ---------- launch ----------
extern "C" void kernel_launch(void* const* d_in, const int* in_sizes, int n_in,
                              void* d_out, int out_size, void* d_ws, size_t ws_size,
                              hipStream_t stream) {
  const float* x      = (const float*)d_in[0];
  const float* key    = (const float*)d_in[1];
  const float* w_off1 = (const float*)d_in[2];
  const float* b_off1 = (const float*)d_in[3];
  const float* w_off2 = (const float*)d_in[4];
  const float* b_off2 = (const float*)d_in[5];
  const float* w_dcn  = (const float*)d_in[6];
  const float* b_dcn  = (const float*)d_in[7];
  const float* w_sel  = (const float*)d_in[8];
  const float* b_sel  = (const float*)d_in[9];
  const float* w_t1   = (const float*)d_in[10];
  const float* w_t2   = (const float*)d_in[11];
  const float* w_t3   = (const float*)d_in[12];
  const float* w_t4   = (const float*)d_in[13];
  const float* w_t5   = (const float*)d_in[14];

  // workspace layout (bytes); peak ~176.5 MiB
  char* ws = (char*)d_ws;
  float* warp = (float*)(ws);                               // [2,288,256,256] f32 = 144 MiB
  float* buf1 = (float*)(ws + 150994944);                   // 16 MiB
  float* buf2 = (float*)(ws + 150994944 + 16777216);        // 16 MiB
  int*   idxb = (int*)  (ws + 150994944 + 2*16777216);      // 0.5 MiB packed top-3
  float* y2   = (float*)(ws);                               // reuse warp region after selconv
  float* y3   = (float*)(ws + 67108864);
  float* out  = (float*)d_out;

  dim3 blk(256);

  // off = lrelu(conv3x3(concat(x,key), w_off1) + b)
  conv3x3_k<64, 8, 16, 1><<<dim3(4, 16, 2 * 4), blk, 0, stream>>>(x, key, 32, w_off1, b_off1, buf1, 32);
  // off = lrelu(conv3x3(off, w_off2) + b)
  conv3x3_k<32, 8, 16, 1><<<dim3(4, 16, 2 * 4), blk, 0, stream>>>(buf1, nullptr, 32, w_off2, b_off2, buf2, 32);
  // warp = conv3x3(concat(key,off), w_dcn) + b   [2,288,H,W]
  conv3x3_k<64, 8, 32, 0><<<dim3(4, 8, 2 * 36), blk, 0, stream>>>(key, buf2, 32, w_dcn, b_dcn, warp, 288);
  // corr + top-3 per pixel
  corr_topk_k<<<dim3(HW / 256, 2), blk, 0, stream>>>(warp, x, idxb);
  // key_warp -> buf2 (off2 dead)
  selconv_k<<<dim3(8, 32, 2), blk, 0, stream>>>(warp, idxb, w_sel, b_sel, buf2);
  // tail
  conv3x3_k<32, 8, 16, 2><<<dim3(4, 16, 2 * 4), blk, 0, stream>>>(buf2, nullptr, 32, w_t1, nullptr, buf1, 32);
  conv1x1_k<32, 16, 2><<<dim3(HW / 1024, 2, 8), blk, 0, stream>>>(buf1, w_t2, y2, 128);
  conv3x3_k<128, 8, 32, 2><<<dim3(4, 8, 2 * 16), blk, 0, stream>>>(y2, nullptr, 128, w_t3, nullptr, y3, 128);
  conv1x1_k<128, 8, 2><<<dim3(HW / 1024, 2, 4), blk, 0, stream>>>(y3, w_t4, buf1, 32);
  conv3x3_k<32, 8, 16, 0><<<dim3(4, 16, 2 * 4), blk, 0, stream>>>(buf1, nullptr, 32, w_t5, nullptr, out, 32);
}

// Round 3
// 5841.062 us; speedup vs baseline: 3.2012x; 3.2012x over previous
//
#include <hip/hip_runtime.h>
#include <math.h>

static constexpr int H = 256, W = 256, HW = H * W;

// ---------- activations ----------
__device__ __forceinline__ float gelu_f(float v) {
  return 0.5f * v * (1.0f + erff(v * 0.70710678118654752440f));
}

template<int ACT>
__device__ __forceinline__ float apply_act(float v) {
  if constexpr (ACT == 1) return v >= 0.f ? v : 0.1f * v;   // LeakyReLU(0.1)
  if constexpr (ACT == 2) return gelu_f(v);
  return v;
}

// ---------- 3x3 same-pad conv, NCHW, f32, weights+inputs staged in LDS ----------
// Tile: 64 wide x TH tall. 256 threads as 16x16: tx=col-group (4 cols),
// ty=row-group (RT=TH/16 rows). OCPB output channels per block.
// blockIdx.x = b*nOcC + ocg  (oc-group fastest -> concurrent blocks share the
// input tile in L2); blockIdx.y = tile-col; blockIdx.z = tile-row.
// NOTE: plain __launch_bounds__(256) — a min-waves arg caps VGPRs and spills.
template<int CIN, int OCPB, int TH, int ACT>
__global__ __launch_bounds__(256)
void conv3x3_k(const float* __restrict__ in0, const float* __restrict__ in1, int cin0,
               const float* __restrict__ w, const float* __restrict__ bias,
               float* __restrict__ out, int ocTotal)
{
  constexpr int CCH = 4;
  constexpr int RT  = TH / 16;          // output rows per thread
  constexpr int IR  = TH + 2;           // staged input rows (halo)
  constexpr int ICOL = 66, ISTR = 68;   // valid cols, padded row stride
  __shared__ __align__(16) float sIn[CCH][IR][ISTR];
  __shared__ __align__(16) float sW[CCH][OCPB][12];

  const int tx = threadIdx.x & 15;
  const int ty = threadIdx.x >> 4;
  const int nOcC = ocTotal / OCPB;
  const int b   = blockIdx.x / nOcC;
  const int oc0 = (blockIdx.x % nOcC) * OCPB;
  const int x0 = blockIdx.y * 64;
  const int y0 = blockIdx.z * TH;

  // staging roles: 4 channels x 64 lanes, row-wise coalesced
  const int sc = threadIdx.x >> 6;
  const int ln = threadIdx.x & 63;

  float acc[OCPB][RT][4];
  #pragma unroll
  for (int o = 0; o < OCPB; ++o) {
    float bv = bias ? bias[oc0 + o] : 0.f;
    #pragma unroll
    for (int r = 0; r < RT; ++r)
      #pragma unroll
      for (int j = 0; j < 4; ++j) acc[o][r][j] = bv;
  }

  #pragma unroll 1
  for (int cc = 0; cc < CIN; cc += CCH) {
    __syncthreads();
    // ---- stage input chunk (with halo, zero-padded at borders) ----
    {
      const int ci = cc + sc;
      const bool first = (ci < cin0);
      const float* tp = first ? in0 : in1;
      const int cT   = first ? cin0 : (CIN - cin0);
      const int cloc = first ? ci : (ci - cin0);
      const float* base = tp + ((size_t)b * cT + cloc) * HW;
      const int gx = x0 + ln - 1;
      const bool vx = (gx >= 0 && gx < W);
      #pragma unroll 2
      for (int r = 0; r < IR; ++r) {
        int gy = y0 + r - 1;
        bool vy = (gy >= 0 && gy < H);
        sIn[sc][r][ln] = (vy && vx) ? base[(size_t)gy * W + gx] : 0.f;
        if (ln < ICOL - 64) {
          int gx2 = gx + 64;
          sIn[sc][r][ln + 64] = (vy && gx2 < W) ? base[(size_t)gy * W + gx2] : 0.f;
        }
      }
    }
    // ---- stage weight chunk (CCH*OCPB*9 floats) ----
    for (int t = threadIdx.x; t < CCH * OCPB * 9; t += 256) {
      int c   = t / (OCPB * 9);
      int rem = t - c * (OCPB * 9);
      int o   = rem / 9;
      int k   = rem - o * 9;
      sW[c][o][k] = w[((size_t)(oc0 + o) * CIN + cc + c) * 9 + k];
    }
    __syncthreads();

    #pragma unroll
    for (int c = 0; c < CCH; ++c) {
      float iv[RT + 2][6];
      #pragma unroll
      for (int r = 0; r < RT + 2; ++r) {
        const float* rp = &sIn[c][ty * RT + r][tx * 4];
        float4 a = *(const float4*)rp;
        float2 bq = *(const float2*)(rp + 4);
        iv[r][0] = a.x; iv[r][1] = a.y; iv[r][2] = a.z; iv[r][3] = a.w;
        iv[r][4] = bq.x; iv[r][5] = bq.y;
      }
      #pragma unroll
      for (int o = 0; o < OCPB; ++o) {
        const float4 wa = *(const float4*)&sW[c][o][0];
        const float4 wb = *(const float4*)&sW[c][o][4];
        const float  w8 = sW[c][o][8];
        #pragma unroll
        for (int r = 0; r < RT; ++r) {
          #pragma unroll
          for (int j = 0; j < 4; ++j) {
            acc[o][r][j] += iv[r + 0][j + 0] * wa.x + iv[r + 0][j + 1] * wa.y + iv[r + 0][j + 2] * wa.z
                          + iv[r + 1][j + 0] * wa.w + iv[r + 1][j + 1] * wb.x + iv[r + 1][j + 2] * wb.y
                          + iv[r + 2][j + 0] * wb.z + iv[r + 2][j + 1] * wb.w + iv[r + 2][j + 2] * w8;
          }
        }
      }
    }
  }

  #pragma unroll
  for (int o = 0; o < OCPB; ++o) {
    #pragma unroll
    for (int r = 0; r < RT; ++r) {
      int oy = y0 + ty * RT + r;
      float4 v;
      v.x = apply_act<ACT>(acc[o][r][0]);
      v.y = apply_act<ACT>(acc[o][r][1]);
      v.z = apply_act<ACT>(acc[o][r][2]);
      v.w = apply_act<ACT>(acc[o][r][3]);
      *(float4*)&out[(((size_t)b * ocTotal + oc0 + o) * H + oy) * W + x0 + tx * 4] = v;
    }
  }
}

// ---------- 1x1 conv, NCHW, f32, weights in LDS, 4 px/thread ----------
template<int CIN, int OCPB, int ACT>
__global__ __launch_bounds__(256)
void conv1x1_k(const float* __restrict__ in, const float* __restrict__ w,
               float* __restrict__ out, int ocTotal)
{
  __shared__ __align__(16) float sW[OCPB][CIN];
  const int b   = blockIdx.y;
  const int oc0 = blockIdx.z * OCPB;
  for (int t = threadIdx.x; t < OCPB * CIN; t += 256)
    sW[t / CIN][t % CIN] = w[(size_t)(oc0 + t / CIN) * CIN + (t % CIN)];
  __syncthreads();

  const int p4 = (blockIdx.x * 256 + threadIdx.x) * 4;
  const float* ip = in + (size_t)b * CIN * HW + p4;
  float acc[OCPB][4];
  #pragma unroll
  for (int o = 0; o < OCPB; ++o)
    #pragma unroll
    for (int j = 0; j < 4; ++j) acc[o][j] = 0.f;

  #pragma unroll 2
  for (int ci = 0; ci < CIN; ci += 4) {
    float4 v0 = *(const float4*)(ip + (size_t)(ci + 0) * HW);
    float4 v1 = *(const float4*)(ip + (size_t)(ci + 1) * HW);
    float4 v2 = *(const float4*)(ip + (size_t)(ci + 2) * HW);
    float4 v3 = *(const float4*)(ip + (size_t)(ci + 3) * HW);
    #pragma unroll
    for (int o = 0; o < OCPB; ++o) {
      const float4 wv = *(const float4*)&sW[o][ci];
      acc[o][0] += v0.x * wv.x + v1.x * wv.y + v2.x * wv.z + v3.x * wv.w;
      acc[o][1] += v0.y * wv.x + v1.y * wv.y + v2.y * wv.z + v3.y * wv.w;
      acc[o][2] += v0.z * wv.x + v1.z * wv.y + v2.z * wv.z + v3.z * wv.w;
      acc[o][3] += v0.w * wv.x + v1.w * wv.y + v2.w * wv.z + v3.w * wv.w;
    }
  }
  #pragma unroll
  for (int o = 0; o < OCPB; ++o) {
    float4 v;
    v.x = apply_act<ACT>(acc[o][0]);
    v.y = apply_act<ACT>(acc[o][1]);
    v.z = apply_act<ACT>(acc[o][2]);
    v.w = apply_act<ACT>(acc[o][3]);
    *(float4*)&out[((size_t)b * ocTotal + oc0 + o) * HW + p4] = v;
  }
}

// ---------- corr (einsum) + top-3 (jax tie-break: lower index wins) ----------
__global__ __launch_bounds__(256)
void corr_topk_k(const float* __restrict__ warp, const float* __restrict__ x,
                 int* __restrict__ idxo)
{
  const int p = blockIdx.x * 256 + threadIdx.x;
  const int b = blockIdx.y;
  float corr[9];
  #pragma unroll
  for (int o = 0; o < 9; ++o) corr[o] = 0.f;
  #pragma unroll 2
  for (int c = 0; c < 32; ++c) {
    float xv = x[((size_t)b * 32 + c) * HW + p];
    const float* wp = warp + ((size_t)b * 288 + (size_t)c * 9) * HW + p;
    #pragma unroll
    for (int o = 0; o < 9; ++o) corr[o] += wp[(size_t)o * HW] * xv;
  }
  unsigned mask = 0;
  int packed = 0;
  #pragma unroll
  for (int t = 0; t < 3; ++t) {
    float best = -INFINITY; int bi = 0;
    #pragma unroll
    for (int o = 0; o < 9; ++o) {
      bool take = (((mask >> o) & 1u) == 0u) && (corr[o] > best);
      best = take ? corr[o] : best;
      bi   = take ? o       : bi;
    }
    mask   |= 1u << bi;
    packed |= bi << (4 * t);
  }
  idxo[(size_t)b * HW + p] = packed;
}

// ---------- gather selected warps + 3x3 conv with w_sel ----------
__global__ __launch_bounds__(256)
void selconv_k(const float* __restrict__ warp, const int* __restrict__ idxp,
               const float* __restrict__ wsel, const float* __restrict__ bsel,
               float* __restrict__ out)
{
  const int tx = threadIdx.x & 31, ty = threadIdx.x >> 5;
  const int px = blockIdx.x * 32 + tx;
  const int py = blockIdx.y * 8 + ty;
  const int b  = blockIdx.z;

  int  nidx[9];
  bool nval[9];
  int  qoff[9];
  #pragma unroll
  for (int kh = 0; kh < 3; ++kh)
    #pragma unroll
    for (int kw = 0; kw < 3; ++kw) {
      int k = kh * 3 + kw;
      int qy = py + kh - 1, qx = px + kw - 1;
      nval[k] = (qy >= 0 && qy < H && qx >= 0 && qx < W);
      qoff[k] = qy * W + qx;
      nidx[k] = nval[k] ? idxp[(size_t)b * HW + qoff[k]] : 0;
    }

  float ws27[27];
  #pragma unroll
  for (int i = 0; i < 27; ++i) ws27[i] = wsel[i];
  const float bs = bsel[0];

  #pragma unroll 1
  for (int c = 0; c < 32; ++c) {
    float acc = bs;
    const float* wb = warp + ((size_t)b * 288 + (size_t)c * 9) * HW;
    #pragma unroll
    for (int k = 0; k < 9; ++k) {
      if (nval[k]) {
        int pk = nidx[k];
        #pragma unroll
        for (int t = 0; t < 3; ++t) {
          int o = (pk >> (4 * t)) & 15;
          acc += ws27[t * 9 + k] * wb[(size_t)o * HW + qoff[k]];
        }
      }
    }
    out[((size_t)b * 32 + c) * HW + (size_t)py * W + px] = acc;
  }
}

// ---------- launch ----------
extern "C" void kernel_launch(void* const* d_in, const int* in_sizes, int n_in,
                              void* d_out, int out_size, void* d_ws, size_t ws_size,
                              hipStream_t stream) {
  const float* x      = (const float*)d_in[0];
  const float* key    = (const float*)d_in[1];
  const float* w_off1 = (const float*)d_in[2];
  const float* b_off1 = (const float*)d_in[3];
  const float* w_off2 = (const float*)d_in[4];
  const float* b_off2 = (const float*)d_in[5];
  const float* w_dcn  = (const float*)d_in[6];
  const float* b_dcn  = (const float*)d_in[7];
  const float* w_sel  = (const float*)d_in[8];
  const float* b_sel  = (const float*)d_in[9];
  const float* w_t1   = (const float*)d_in[10];
  const float* w_t2   = (const float*)d_in[11];
  const float* w_t3   = (const float*)d_in[12];
  const float* w_t4   = (const float*)d_in[13];
  const float* w_t5   = (const float*)d_in[14];

  // workspace layout (bytes); peak ~176.5 MiB
  char* ws = (char*)d_ws;
  float* warp = (float*)(ws);                               // [2,288,256,256] f32 = 144 MiB
  float* buf1 = (float*)(ws + 150994944);                   // 16 MiB
  float* buf2 = (float*)(ws + 150994944 + 16777216);        // 16 MiB
  int*   idxb = (int*)  (ws + 150994944 + 2*16777216);      // 0.5 MiB packed top-3
  float* y2   = (float*)(ws);                               // reuse warp region after selconv
  float* y3   = (float*)(ws + 67108864);
  float* out  = (float*)d_out;

  dim3 blk(256);

  // off = lrelu(conv3x3(concat(x,key), w_off1) + b)    grid.x = b*nOcC
  conv3x3_k<64, 8, 16, 1><<<dim3(2 * 4, 4, 16), blk, 0, stream>>>(x, key, 32, w_off1, b_off1, buf1, 32);
  // off = lrelu(conv3x3(off, w_off2) + b)
  conv3x3_k<32, 8, 16, 1><<<dim3(2 * 4, 4, 16), blk, 0, stream>>>(buf1, nullptr, 32, w_off2, b_off2, buf2, 32);
  // warp = conv3x3(concat(key,off), w_dcn) + b   [2,288,H,W]
  conv3x3_k<64, 8, 32, 0><<<dim3(2 * 36, 4, 8), blk, 0, stream>>>(key, buf2, 32, w_dcn, b_dcn, warp, 288);
  // corr + top-3 per pixel
  corr_topk_k<<<dim3(HW / 256, 2), blk, 0, stream>>>(warp, x, idxb);
  // key_warp -> buf2 (off2 dead)
  selconv_k<<<dim3(8, 32, 2), blk, 0, stream>>>(warp, idxb, w_sel, b_sel, buf2);
  // tail
  conv3x3_k<32, 8, 16, 2><<<dim3(2 * 4, 4, 16), blk, 0, stream>>>(buf2, nullptr, 32, w_t1, nullptr, buf1, 32);
  conv1x1_k<32, 16, 2><<<dim3(HW / 1024, 2, 8), blk, 0, stream>>>(buf1, w_t2, y2, 128);
  conv3x3_k<128, 8, 32, 2><<<dim3(2 * 16, 4, 8), blk, 0, stream>>>(y2, nullptr, 128, w_t3, nullptr, y3, 128);
  conv1x1_k<128, 8, 2><<<dim3(HW / 1024, 2, 4), blk, 0, stream>>>(y3, w_t4, buf1, 32);
  conv3x3_k<32, 8, 16, 0><<<dim3(2 * 4, 4, 16), blk, 0, stream>>>(buf1, nullptr, 32, w_t5, nullptr, out, 32);
}

// Round 4
// 2692.887 us; speedup vs baseline: 6.9437x; 2.1691x over previous
//
#include <hip/hip_runtime.h>
#include <math.h>

static constexpr int H = 256, W = 256, HW = H * W;

// ---------- activations ----------
__device__ __forceinline__ float gelu_f(float v) {
  return 0.5f * v * (1.0f + erff(v * 0.70710678118654752440f));
}

template<int ACT>
__device__ __forceinline__ float apply_act(float v) {
  if constexpr (ACT == 1) return v >= 0.f ? v : 0.1f * v;   // LeakyReLU(0.1)
  if constexpr (ACT == 2) return gelu_f(v);
  return v;
}

// ---------- 3x3 same-pad conv, NCHW, f32 ----------
// Tile 64x16 output px. 256 threads: thread -> 1 row x 4 cols (float4).
//   row = (wave<<2) + (lane>>4), colgrp = lane&15.
// A wave's b128 LDS read = 4 consecutive rows x 16 colgrps -> every bank hit
// exactly 8x per 1KB access = conflict-free minimum.
// OCPB output channels per block; input channels staged in LDS 4 at a time
// (one wave stages one channel plane, 64-lane coalesced rows).
// Weights staged in LDS, read as broadcasts. c-loop kept unroll(1) to bound
// live registers (round-3 lesson: full unroll -> 248 VGPR -> 11% occupancy).
template<int CIN, int OCPB, int ACT>
__global__ __launch_bounds__(256)
void conv3x3_k(const float* __restrict__ in0, const float* __restrict__ in1, int cin0,
               const float* __restrict__ w, const float* __restrict__ bias,
               float* __restrict__ out, int ocTotal)
{
  constexpr int CCH = 4;
  constexpr int IR  = 18;               // staged rows (16 + halo)
  constexpr int ISTR = 68;              // padded row stride (dwords, 16B-mult)
  __shared__ __align__(16) float sIn[CCH][IR][ISTR];   // 19584 B
  __shared__ __align__(16) float sW[CCH][OCPB][12];

  const int lane = threadIdx.x & 63;
  const int wv   = threadIdx.x >> 6;            // 0..3
  const int tx   = lane & 15;                   // col group (4 px)
  const int row  = (wv << 2) + (lane >> 4);     // output row in tile, 0..15

  const int nOcC = ocTotal / OCPB;
  const int b   = blockIdx.x / nOcC;
  const int oc0 = (blockIdx.x % nOcC) * OCPB;
  const int x0  = blockIdx.y * 64;
  const int y0  = blockIdx.z * 16;

  float acc[OCPB][4];
  #pragma unroll
  for (int o = 0; o < OCPB; ++o) {
    float bv = bias ? bias[oc0 + o] : 0.f;
    #pragma unroll
    for (int j = 0; j < 4; ++j) acc[o][j] = bv;
  }

  const int gx  = x0 + lane - 1;                // staging column for this lane
  const bool vx = (gx >= 0 && gx < W);

  #pragma unroll 1
  for (int cc = 0; cc < CIN; cc += CCH) {
    __syncthreads();
    // ---- stage input: wave wv stages channel cc+wv (rows coalesced) ----
    {
      const int ci = cc + wv;
      const bool first = (ci < cin0);
      const float* tp = first ? in0 : in1;
      const int cT   = first ? cin0 : (CIN - cin0);
      const int cloc = first ? ci : (ci - cin0);
      const float* base = tp + ((size_t)b * cT + cloc) * HW;
      #pragma unroll 2
      for (int r = 0; r < IR; ++r) {
        int gy = y0 + r - 1;
        bool vy = (gy >= 0 && gy < H);
        sIn[wv][r][lane] = (vy && vx) ? base[(size_t)gy * W + gx] : 0.f;
        if (lane < 2) {
          int gx2 = gx + 64;
          sIn[wv][r][lane + 64] = (vy && gx2 < W) ? base[(size_t)gy * W + gx2] : 0.f;
        }
      }
    }
    // ---- stage weights: CCH*OCPB*9 floats ----
    for (int t = threadIdx.x; t < CCH * OCPB * 9; t += 256) {
      int c   = t / (OCPB * 9);
      int rem = t - c * (OCPB * 9);
      int o   = rem / 9;
      int k   = rem - o * 9;
      sW[c][o][k] = w[((size_t)(oc0 + o) * CIN + cc + c) * 9 + k];
    }
    __syncthreads();

    #pragma unroll 1
    for (int c = 0; c < CCH; ++c) {
      float iv[3][6];
      #pragma unroll
      for (int kh = 0; kh < 3; ++kh) {
        const float* rp = &sIn[c][row + kh][tx * 4];
        float4 a  = *(const float4*)rp;
        float2 b2 = *(const float2*)(rp + 4);
        iv[kh][0] = a.x;  iv[kh][1] = a.y;  iv[kh][2] = a.z;  iv[kh][3] = a.w;
        iv[kh][4] = b2.x; iv[kh][5] = b2.y;
      }
      #pragma unroll
      for (int o = 0; o < OCPB; ++o) {
        const float4 wa = *(const float4*)&sW[c][o][0];
        const float4 wb = *(const float4*)&sW[c][o][4];
        const float  w8 = sW[c][o][8];
        #pragma unroll
        for (int j = 0; j < 4; ++j) {
          acc[o][j] += iv[0][j + 0] * wa.x + iv[0][j + 1] * wa.y + iv[0][j + 2] * wa.z
                     + iv[1][j + 0] * wa.w + iv[1][j + 1] * wb.x + iv[1][j + 2] * wb.y
                     + iv[2][j + 0] * wb.z + iv[2][j + 1] * wb.w + iv[2][j + 2] * w8;
        }
      }
    }
  }

  #pragma unroll
  for (int o = 0; o < OCPB; ++o) {
    float4 v;
    v.x = apply_act<ACT>(acc[o][0]);
    v.y = apply_act<ACT>(acc[o][1]);
    v.z = apply_act<ACT>(acc[o][2]);
    v.w = apply_act<ACT>(acc[o][3]);
    *(float4*)&out[(((size_t)b * ocTotal + oc0 + o) * H + y0 + row) * W + x0 + tx * 4] = v;
  }
}

// ---------- 1x1 conv, NCHW, f32, weights in LDS, 4 px/thread ----------
template<int CIN, int OCPB, int ACT>
__global__ __launch_bounds__(256)
void conv1x1_k(const float* __restrict__ in, const float* __restrict__ w,
               float* __restrict__ out, int ocTotal)
{
  __shared__ __align__(16) float sW[OCPB][CIN];
  const int b   = blockIdx.y;
  const int oc0 = blockIdx.z * OCPB;
  for (int t = threadIdx.x; t < OCPB * CIN; t += 256)
    sW[t / CIN][t % CIN] = w[(size_t)(oc0 + t / CIN) * CIN + (t % CIN)];
  __syncthreads();

  const int p4 = (blockIdx.x * 256 + threadIdx.x) * 4;
  const float* ip = in + (size_t)b * CIN * HW + p4;
  float acc[OCPB][4];
  #pragma unroll
  for (int o = 0; o < OCPB; ++o)
    #pragma unroll
    for (int j = 0; j < 4; ++j) acc[o][j] = 0.f;

  #pragma unroll 2
  for (int ci = 0; ci < CIN; ci += 4) {
    float4 v0 = *(const float4*)(ip + (size_t)(ci + 0) * HW);
    float4 v1 = *(const float4*)(ip + (size_t)(ci + 1) * HW);
    float4 v2 = *(const float4*)(ip + (size_t)(ci + 2) * HW);
    float4 v3 = *(const float4*)(ip + (size_t)(ci + 3) * HW);
    #pragma unroll
    for (int o = 0; o < OCPB; ++o) {
      const float4 wv = *(const float4*)&sW[o][ci];
      acc[o][0] += v0.x * wv.x + v1.x * wv.y + v2.x * wv.z + v3.x * wv.w;
      acc[o][1] += v0.y * wv.x + v1.y * wv.y + v2.y * wv.z + v3.y * wv.w;
      acc[o][2] += v0.z * wv.x + v1.z * wv.y + v2.z * wv.z + v3.z * wv.w;
      acc[o][3] += v0.w * wv.x + v1.w * wv.y + v2.w * wv.z + v3.w * wv.w;
    }
  }
  #pragma unroll
  for (int o = 0; o < OCPB; ++o) {
    float4 v;
    v.x = apply_act<ACT>(acc[o][0]);
    v.y = apply_act<ACT>(acc[o][1]);
    v.z = apply_act<ACT>(acc[o][2]);
    v.w = apply_act<ACT>(acc[o][3]);
    *(float4*)&out[((size_t)b * ocTotal + oc0 + o) * HW + p4] = v;
  }
}

// ---------- corr (einsum) + top-3 (jax tie-break: lower index wins) ----------
__global__ __launch_bounds__(256)
void corr_topk_k(const float* __restrict__ warp, const float* __restrict__ x,
                 int* __restrict__ idxo)
{
  const int p = blockIdx.x * 256 + threadIdx.x;
  const int b = blockIdx.y;
  float corr[9];
  #pragma unroll
  for (int o = 0; o < 9; ++o) corr[o] = 0.f;
  #pragma unroll 2
  for (int c = 0; c < 32; ++c) {
    float xv = x[((size_t)b * 32 + c) * HW + p];
    const float* wp = warp + ((size_t)b * 288 + (size_t)c * 9) * HW + p;
    #pragma unroll
    for (int o = 0; o < 9; ++o) corr[o] += wp[(size_t)o * HW] * xv;
  }
  unsigned mask = 0;
  int packed = 0;
  #pragma unroll
  for (int t = 0; t < 3; ++t) {
    float best = -INFINITY; int bi = 0;
    #pragma unroll
    for (int o = 0; o < 9; ++o) {
      bool take = (((mask >> o) & 1u) == 0u) && (corr[o] > best);
      best = take ? corr[o] : best;
      bi   = take ? o       : bi;
    }
    mask   |= 1u << bi;
    packed |= bi << (4 * t);
  }
  idxo[(size_t)b * HW + p] = packed;
}

// ---------- gather selected warps + 3x3 conv with w_sel ----------
__global__ __launch_bounds__(256)
void selconv_k(const float* __restrict__ warp, const int* __restrict__ idxp,
               const float* __restrict__ wsel, const float* __restrict__ bsel,
               float* __restrict__ out)
{
  const int tx = threadIdx.x & 31, ty = threadIdx.x >> 5;
  const int px = blockIdx.x * 32 + tx;
  const int py = blockIdx.y * 8 + ty;
  const int b  = blockIdx.z;

  int  nidx[9];
  bool nval[9];
  int  qoff[9];
  #pragma unroll
  for (int kh = 0; kh < 3; ++kh)
    #pragma unroll
    for (int kw = 0; kw < 3; ++kw) {
      int k = kh * 3 + kw;
      int qy = py + kh - 1, qx = px + kw - 1;
      nval[k] = (qy >= 0 && qy < H && qx >= 0 && qx < W);
      qoff[k] = qy * W + qx;
      nidx[k] = nval[k] ? idxp[(size_t)b * HW + qoff[k]] : 0;
    }

  float ws27[27];
  #pragma unroll
  for (int i = 0; i < 27; ++i) ws27[i] = wsel[i];
  const float bs = bsel[0];

  #pragma unroll 1
  for (int c = 0; c < 32; ++c) {
    float acc = bs;
    const float* wb = warp + ((size_t)b * 288 + (size_t)c * 9) * HW;
    #pragma unroll
    for (int k = 0; k < 9; ++k) {
      if (nval[k]) {
        int pk = nidx[k];
        #pragma unroll
        for (int t = 0; t < 3; ++t) {
          int o = (pk >> (4 * t)) & 15;
          acc += ws27[t * 9 + k] * wb[(size_t)o * HW + qoff[k]];
        }
      }
    }
    out[((size_t)b * 32 + c) * HW + (size_t)py * W + px] = acc;
  }
}

// ---------- launch ----------
extern "C" void kernel_launch(void* const* d_in, const int* in_sizes, int n_in,
                              void* d_out, int out_size, void* d_ws, size_t ws_size,
                              hipStream_t stream) {
  const float* x      = (const float*)d_in[0];
  const float* key    = (const float*)d_in[1];
  const float* w_off1 = (const float*)d_in[2];
  const float* b_off1 = (const float*)d_in[3];
  const float* w_off2 = (const float*)d_in[4];
  const float* b_off2 = (const float*)d_in[5];
  const float* w_dcn  = (const float*)d_in[6];
  const float* b_dcn  = (const float*)d_in[7];
  const float* w_sel  = (const float*)d_in[8];
  const float* b_sel  = (const float*)d_in[9];
  const float* w_t1   = (const float*)d_in[10];
  const float* w_t2   = (const float*)d_in[11];
  const float* w_t3   = (const float*)d_in[12];
  const float* w_t4   = (const float*)d_in[13];
  const float* w_t5   = (const float*)d_in[14];

  // workspace layout (bytes); peak ~176.5 MiB
  char* ws = (char*)d_ws;
  float* warp = (float*)(ws);                               // [2,288,256,256] f32 = 144 MiB
  float* buf1 = (float*)(ws + 150994944);                   // 16 MiB
  float* buf2 = (float*)(ws + 150994944 + 16777216);        // 16 MiB
  int*   idxb = (int*)  (ws + 150994944 + 2*16777216);      // 0.5 MiB packed top-3
  float* y2   = (float*)(ws);                               // reuse warp region after selconv
  float* y3   = (float*)(ws + 67108864);
  float* out  = (float*)d_out;

  dim3 blk(256);

  // off = lrelu(conv3x3(concat(x,key), w_off1) + b)   grid.x = b*nOcC (oc fastest)
  conv3x3_k<64, 8, 1><<<dim3(2 * 4, 4, 16), blk, 0, stream>>>(x, key, 32, w_off1, b_off1, buf1, 32);
  // off = lrelu(conv3x3(off, w_off2) + b)
  conv3x3_k<32, 8, 1><<<dim3(2 * 4, 4, 16), blk, 0, stream>>>(buf1, nullptr, 32, w_off2, b_off2, buf2, 32);
  // warp = conv3x3(concat(key,off), w_dcn) + b   [2,288,H,W]
  conv3x3_k<64, 8, 0><<<dim3(2 * 36, 4, 16), blk, 0, stream>>>(key, buf2, 32, w_dcn, b_dcn, warp, 288);
  // corr + top-3 per pixel
  corr_topk_k<<<dim3(HW / 256, 2), blk, 0, stream>>>(warp, x, idxb);
  // key_warp -> buf2 (off2 dead)
  selconv_k<<<dim3(8, 32, 2), blk, 0, stream>>>(warp, idxb, w_sel, b_sel, buf2);
  // tail
  conv3x3_k<32, 8, 2><<<dim3(2 * 4, 4, 16), blk, 0, stream>>>(buf2, nullptr, 32, w_t1, nullptr, buf1, 32);
  conv1x1_k<32, 16, 2><<<dim3(HW / 1024, 2, 8), blk, 0, stream>>>(buf1, w_t2, y2, 128);
  conv3x3_k<128, 8, 2><<<dim3(2 * 16, 4, 16), blk, 0, stream>>>(y2, nullptr, 128, w_t3, nullptr, y3, 128);
  conv1x1_k<128, 8, 2><<<dim3(HW / 1024, 2, 4), blk, 0, stream>>>(y3, w_t4, buf1, 32);
  conv3x3_k<32, 8, 0><<<dim3(2 * 4, 4, 16), blk, 0, stream>>>(buf1, nullptr, 32, w_t5, nullptr, out, 32);
}

// Round 5
// 1876.058 us; speedup vs baseline: 9.9669x; 1.4354x over previous
//
#include <hip/hip_runtime.h>
#include <math.h>

static constexpr int H = 256, W = 256, HW = H * W;

typedef __attribute__((ext_vector_type(8))) short short8v;   // 8 bf16 (4 VGPR)
typedef __attribute__((ext_vector_type(4))) float float4v;   // MFMA acc

// ---------- bf16 helpers (RN-even) ----------
__device__ __forceinline__ unsigned short f2bf_rn(float f) {
  unsigned u = __float_as_uint(f);
  unsigned r = (u + 0x7FFFu + ((u >> 16) & 1u)) >> 16;
  return (unsigned short)r;
}
__device__ __forceinline__ float bf2f(unsigned short h) {
  return __uint_as_float((unsigned)h << 16);
}

// ---------- activations ----------
__device__ __forceinline__ float gelu_f(float v) {
  return 0.5f * v * (1.0f + erff(v * 0.70710678118654752440f));
}
template<int ACT>
__device__ __forceinline__ float apply_act(float v) {
  if constexpr (ACT == 1) return v >= 0.f ? v : 0.1f * v;   // LeakyReLU(0.1)
  if constexpr (ACT == 2) return gelu_f(v);
  return v;
}

// ---------- 3x3 conv, f32 vector path (exact; feeds the top-k) ----------
// Tile 64x16. lane = column (scalar b32 LDS reads -> 64 consecutive dwords/wave
// = 2 lanes/bank = conflict-free minimum). Wave wv owns rows wv*4..wv*4+3.
// Weights in LDS, read as wave-uniform b128 broadcasts.
template<int CIN, int OCPB, int ACT>
__global__ __launch_bounds__(256)
void conv3x3_k(const float* __restrict__ in0, const float* __restrict__ in1, int cin0,
               const float* __restrict__ w, const float* __restrict__ bias,
               float* __restrict__ out, int ocTotal)
{
  constexpr int CCH = 4;
  __shared__ float sIn[CCH][18][66];
  __shared__ __align__(16) float sW[CCH][OCPB][12];

  const int lane = threadIdx.x & 63;
  const int wv   = threadIdx.x >> 6;

  const int nOcC = ocTotal / OCPB;
  const int b   = blockIdx.x / nOcC;
  const int oc0 = (blockIdx.x % nOcC) * OCPB;
  const int x0  = blockIdx.y * 64;
  const int y0  = blockIdx.z * 16;

  float acc[OCPB][4];
  #pragma unroll
  for (int o = 0; o < OCPB; ++o) {
    float bv = bias ? bias[oc0 + o] : 0.f;
    #pragma unroll
    for (int r = 0; r < 4; ++r) acc[o][r] = bv;
  }

  const int gx  = x0 + lane - 1;
  const bool vx = (gx >= 0 && gx < W);

  #pragma unroll 1
  for (int cc = 0; cc < CIN; cc += CCH) {
    __syncthreads();
    {   // wave wv stages channel cc+wv (rows coalesced)
      const int ci = cc + wv;
      const bool first = (ci < cin0);
      const float* tp = first ? in0 : in1;
      const int cT   = first ? cin0 : (CIN - cin0);
      const int cloc = first ? ci : (ci - cin0);
      const float* base = tp + ((size_t)b * cT + cloc) * HW;
      #pragma unroll 2
      for (int r = 0; r < 18; ++r) {
        int gy = y0 + r - 1;
        bool vy = (gy >= 0 && gy < H);
        sIn[wv][r][lane] = (vy && vx) ? base[(size_t)gy * W + gx] : 0.f;
        if (lane < 2) {
          int gx2 = gx + 64;
          sIn[wv][r][lane + 64] = (vy && gx2 < W) ? base[(size_t)gy * W + gx2] : 0.f;
        }
      }
    }
    for (int t = threadIdx.x; t < CCH * OCPB * 9; t += 256) {
      int c   = t / (OCPB * 9);
      int rem = t - c * (OCPB * 9);
      int o   = rem / 9;
      int k   = rem - o * 9;
      sW[c][o][k] = w[((size_t)(oc0 + o) * CIN + cc + c) * 9 + k];
    }
    __syncthreads();

    #pragma unroll 1
    for (int c = 0; c < CCH; ++c) {
      float iv[6][3];
      #pragma unroll
      for (int rr = 0; rr < 6; ++rr)
        #pragma unroll
        for (int dx = 0; dx < 3; ++dx)
          iv[rr][dx] = sIn[c][wv * 4 + rr][lane + dx];
      #pragma unroll
      for (int o = 0; o < OCPB; ++o) {
        const float4 wa = *(const float4*)&sW[c][o][0];
        const float4 wb = *(const float4*)&sW[c][o][4];
        const float  w8 = sW[c][o][8];
        #pragma unroll
        for (int r = 0; r < 4; ++r) {
          acc[o][r] += iv[r + 0][0] * wa.x + iv[r + 0][1] * wa.y + iv[r + 0][2] * wa.z
                     + iv[r + 1][0] * wa.w + iv[r + 1][1] * wb.x + iv[r + 1][2] * wb.y
                     + iv[r + 2][0] * wb.z + iv[r + 2][1] * wb.w + iv[r + 2][2] * w8;
        }
      }
    }
  }

  #pragma unroll
  for (int o = 0; o < OCPB; ++o)
    #pragma unroll
    for (int r = 0; r < 4; ++r)
      out[(((size_t)b * ocTotal + oc0 + o) * H + y0 + wv * 4 + r) * W + x0 + lane]
          = apply_act<ACT>(acc[o][r]);
}

// ---------- weight prep for MFMA tail: [OC][CIN][3][3] f32 -> [tap][OC][CIN] bf16 hi/lo ----------
__global__ __launch_bounds__(256)
void prep_w_k(const float* __restrict__ w, unsigned short* __restrict__ hi,
              unsigned short* __restrict__ lo, int OC, int CIN)
{
  int tid = blockIdx.x * 256 + threadIdx.x;
  if (tid >= OC * CIN * 9) return;
  int ci = tid % CIN; int r = tid / CIN; int oc = r % OC; int tap = r / OC;
  float v = w[((size_t)oc * CIN + ci) * 9 + tap];
  unsigned short h = f2bf_rn(v);
  hi[tid] = h;
  lo[tid] = f2bf_rn(v - bf2f(h));
}

// ---------- 3x3 conv, bf16 MFMA split-3 path (tail; ~4e-6 relative error) ----------
// Implicit GEMM: out[oc][px] = sum_{tap,ci} w[oc][tap][ci] * im_tap[ci][px].
// Block: 256 thr = 4 waves; tile = 32 oc x (64 cols x 4 rows) px. Wave wv owns
// output row y0+wv, all 64 cols, 32 oc. MFMA 16x16x32: A row=l&15 (oc),
// k=(l>>4)*8+j (ci); B col=l&15 (px), same k; D col=l&15, row=(l>>4)*4+reg.
// LDS input tile: [6 rows][66 cols][9 granules x 16B] (8 used: 4 hi + 4 lo,
// 1 pad) -> col stride 144B = 9 quad-banks => (9c+g) mod 8 covers all 8
// quad-banks => conflict-free b128 reads AND writes.
template<int CIN, int OC, int ACT>
__global__ __launch_bounds__(256)
void conv3x3_mfma_k(const float* __restrict__ in,
                    const unsigned short* __restrict__ wtHi,
                    const unsigned short* __restrict__ wtLo,
                    float* __restrict__ out)
{
  __shared__ unsigned short sB[6 * 66 * 72];   // 57,024 B

  const int l  = threadIdx.x & 63;
  const int wv = threadIdx.x >> 6;
  const int nOc = OC / 32;
  const int b   = blockIdx.x / nOc;
  const int oc0 = (blockIdx.x % nOc) * 32;
  const int x0  = blockIdx.y * 64;
  const int y0  = blockIdx.z * 4;

  float4v acc[2][4];
  #pragma unroll
  for (int of = 0; of < 2; ++of)
    #pragma unroll
    for (int f = 0; f < 4; ++f)
      acc[of][f] = (float4v){0.f, 0.f, 0.f, 0.f};

  const int gx_m  = x0 + l - 1;
  const bool vx_m = (gx_m >= 0 && gx_m < W);
  const int gx_e  = gx_m + 64;                 // cols 64,65 for l<2
  const bool vx_e = (l < 2) && (gx_e < W);

  const int k8  = (l >> 4) * 8;
  const int ocl = l & 15;

  #pragma unroll 1
  for (int cc = 0; cc < CIN; cc += 32) {
    __syncthreads();
    // ---- stage: 24 tasks (6 rows x 4 ch-granules), round-robin over waves ----
    #pragma unroll 1
    for (int t = wv; t < 24; t += 4) {
      int r = t >> 2, g = t & 3;
      int gy = y0 + r - 1;
      bool vy = (gy >= 0 && gy < H);
      short8v h8 = (short8v)0, l8 = (short8v)0, h8e = (short8v)0, l8e = (short8v)0;
      if (vy) {
        const float* rowp = in + ((size_t)(b * CIN + cc + g * 8) * H + gy) * W;
        #pragma unroll
        for (int k = 0; k < 8; ++k) {
          float v = vx_m ? rowp[(size_t)k * HW + gx_m] : 0.f;
          unsigned short h = f2bf_rn(v);
          h8[k] = (short)h;
          l8[k] = (short)f2bf_rn(v - bf2f(h));
          float ve = vx_e ? rowp[(size_t)k * HW + gx_e] : 0.f;
          unsigned short he = f2bf_rn(ve);
          h8e[k] = (short)he;
          l8e[k] = (short)f2bf_rn(ve - bf2f(he));
        }
      }
      int base = (r * 66 + l) * 72 + g * 8;
      *(short8v*)&sB[base]      = h8;
      *(short8v*)&sB[base + 32] = l8;
      if (l < 2) {
        int basee = (r * 66 + 64 + l) * 72 + g * 8;
        *(short8v*)&sB[basee]      = h8e;
        *(short8v*)&sB[basee + 32] = l8e;
      }
    }
    __syncthreads();

    #pragma unroll 1
    for (int tap = 0; tap < 9; ++tap) {
      const int dy = tap / 3, dx = tap - 3 * (tap / 3);
      // A fragments from global (small, L2-hot): lane -> oc=oc0+ocl(+16), k=cc+k8..+7
      const unsigned short* whp = wtHi + (size_t)(tap * OC + oc0 + ocl) * CIN + cc + k8;
      const unsigned short* wlp = wtLo + (size_t)(tap * OC + oc0 + ocl) * CIN + cc + k8;
      short8v ah0 = *(const short8v*)whp;
      short8v ah1 = *(const short8v*)(whp + (size_t)16 * CIN);
      short8v al0 = *(const short8v*)wlp;
      short8v al1 = *(const short8v*)(wlp + (size_t)16 * CIN);
      const int brow = ((wv + dy) * 66 + ocl + dx) * 72 + k8;
      #pragma unroll
      for (int f = 0; f < 4; ++f) {
        short8v bh = *(const short8v*)&sB[brow + f * 16 * 72];
        short8v bl = *(const short8v*)&sB[brow + f * 16 * 72 + 32];
        acc[0][f] = __builtin_amdgcn_mfma_f32_16x16x32_bf16(ah0, bh, acc[0][f], 0, 0, 0);
        acc[0][f] = __builtin_amdgcn_mfma_f32_16x16x32_bf16(ah0, bl, acc[0][f], 0, 0, 0);
        acc[0][f] = __builtin_amdgcn_mfma_f32_16x16x32_bf16(al0, bh, acc[0][f], 0, 0, 0);
        acc[1][f] = __builtin_amdgcn_mfma_f32_16x16x32_bf16(ah1, bh, acc[1][f], 0, 0, 0);
        acc[1][f] = __builtin_amdgcn_mfma_f32_16x16x32_bf16(ah1, bl, acc[1][f], 0, 0, 0);
        acc[1][f] = __builtin_amdgcn_mfma_f32_16x16x32_bf16(al1, bh, acc[1][f], 0, 0, 0);
      }
    }
  }

  // ---- epilogue: D col=l&15 (px), row=(l>>4)*4+reg (oc) ----
  #pragma unroll
  for (int of = 0; of < 2; ++of)
    #pragma unroll
    for (int f = 0; f < 4; ++f)
      #pragma unroll
      for (int r = 0; r < 4; ++r) {
        int oc = oc0 + of * 16 + (l >> 4) * 4 + r;
        int px = x0 + f * 16 + (l & 15);
        out[((size_t)(b * OC + oc) * H + (y0 + wv)) * W + px] = apply_act<ACT>(acc[of][f][r]);
      }
}

// ---------- 1x1 conv, f32 ----------
template<int CIN, int OCPB, int ACT>
__global__ __launch_bounds__(256)
void conv1x1_k(const float* __restrict__ in, const float* __restrict__ w,
               float* __restrict__ out, int ocTotal)
{
  __shared__ __align__(16) float sW[OCPB][CIN];
  const int b   = blockIdx.y;
  const int oc0 = blockIdx.z * OCPB;
  for (int t = threadIdx.x; t < OCPB * CIN; t += 256)
    sW[t / CIN][t % CIN] = w[(size_t)(oc0 + t / CIN) * CIN + (t % CIN)];
  __syncthreads();

  const int p4 = (blockIdx.x * 256 + threadIdx.x) * 4;
  const float* ip = in + (size_t)b * CIN * HW + p4;
  float acc[OCPB][4];
  #pragma unroll
  for (int o = 0; o < OCPB; ++o)
    #pragma unroll
    for (int j = 0; j < 4; ++j) acc[o][j] = 0.f;

  #pragma unroll 2
  for (int ci = 0; ci < CIN; ci += 4) {
    float4 v0 = *(const float4*)(ip + (size_t)(ci + 0) * HW);
    float4 v1 = *(const float4*)(ip + (size_t)(ci + 1) * HW);
    float4 v2 = *(const float4*)(ip + (size_t)(ci + 2) * HW);
    float4 v3 = *(const float4*)(ip + (size_t)(ci + 3) * HW);
    #pragma unroll
    for (int o = 0; o < OCPB; ++o) {
      const float4 wv = *(const float4*)&sW[o][ci];
      acc[o][0] += v0.x * wv.x + v1.x * wv.y + v2.x * wv.z + v3.x * wv.w;
      acc[o][1] += v0.y * wv.x + v1.y * wv.y + v2.y * wv.z + v3.y * wv.w;
      acc[o][2] += v0.z * wv.x + v1.z * wv.y + v2.z * wv.z + v3.z * wv.w;
      acc[o][3] += v0.w * wv.x + v1.w * wv.y + v2.w * wv.z + v3.w * wv.w;
    }
  }
  #pragma unroll
  for (int o = 0; o < OCPB; ++o) {
    float4 v;
    v.x = apply_act<ACT>(acc[o][0]);
    v.y = apply_act<ACT>(acc[o][1]);
    v.z = apply_act<ACT>(acc[o][2]);
    v.w = apply_act<ACT>(acc[o][3]);
    *(float4*)&out[((size_t)b * ocTotal + oc0 + o) * HW + p4] = v;
  }
}

// ---------- corr + top-3 (jax tie-break: lower index wins) ----------
__global__ __launch_bounds__(256)
void corr_topk_k(const float* __restrict__ warp, const float* __restrict__ x,
                 int* __restrict__ idxo)
{
  const int p = blockIdx.x * 256 + threadIdx.x;
  const int b = blockIdx.y;
  float corr[9];
  #pragma unroll
  for (int o = 0; o < 9; ++o) corr[o] = 0.f;
  #pragma unroll 2
  for (int c = 0; c < 32; ++c) {
    float xv = x[((size_t)b * 32 + c) * HW + p];
    const float* wp = warp + ((size_t)b * 288 + (size_t)c * 9) * HW + p;
    #pragma unroll
    for (int o = 0; o < 9; ++o) corr[o] += wp[(size_t)o * HW] * xv;
  }
  unsigned mask = 0;
  int packed = 0;
  #pragma unroll
  for (int t = 0; t < 3; ++t) {
    float best = -INFINITY; int bi = 0;
    #pragma unroll
    for (int o = 0; o < 9; ++o) {
      bool take = (((mask >> o) & 1u) == 0u) && (corr[o] > best);
      best = take ? corr[o] : best;
      bi   = take ? o       : bi;
    }
    mask   |= 1u << bi;
    packed |= bi << (4 * t);
  }
  idxo[(size_t)b * HW + p] = packed;
}

// ---------- gather selected warps + 3x3 conv with w_sel ----------
__global__ __launch_bounds__(256)
void selconv_k(const float* __restrict__ warp, const int* __restrict__ idxp,
               const float* __restrict__ wsel, const float* __restrict__ bsel,
               float* __restrict__ out)
{
  const int tx = threadIdx.x & 31, ty = threadIdx.x >> 5;
  const int px = blockIdx.x * 32 + tx;
  const int py = blockIdx.y * 8 + ty;
  const int b  = blockIdx.z;

  int  nidx[9];
  bool nval[9];
  int  qoff[9];
  #pragma unroll
  for (int kh = 0; kh < 3; ++kh)
    #pragma unroll
    for (int kw = 0; kw < 3; ++kw) {
      int k = kh * 3 + kw;
      int qy = py + kh - 1, qx = px + kw - 1;
      nval[k] = (qy >= 0 && qy < H && qx >= 0 && qx < W);
      qoff[k] = qy * W + qx;
      nidx[k] = nval[k] ? idxp[(size_t)b * HW + qoff[k]] : 0;
    }

  float ws27[27];
  #pragma unroll
  for (int i = 0; i < 27; ++i) ws27[i] = wsel[i];
  const float bs = bsel[0];

  #pragma unroll 1
  for (int c = 0; c < 32; ++c) {
    float acc = bs;
    const float* wb = warp + ((size_t)b * 288 + (size_t)c * 9) * HW;
    #pragma unroll
    for (int k = 0; k < 9; ++k) {
      if (nval[k]) {
        int pk = nidx[k];
        #pragma unroll
        for (int t = 0; t < 3; ++t) {
          int o = (pk >> (4 * t)) & 15;
          acc += ws27[t * 9 + k] * wb[(size_t)o * HW + qoff[k]];
        }
      }
    }
    out[((size_t)b * 32 + c) * HW + (size_t)py * W + px] = acc;
  }
}

// ---------- launch ----------
extern "C" void kernel_launch(void* const* d_in, const int* in_sizes, int n_in,
                              void* d_out, int out_size, void* d_ws, size_t ws_size,
                              hipStream_t stream) {
  const float* x      = (const float*)d_in[0];
  const float* key    = (const float*)d_in[1];
  const float* w_off1 = (const float*)d_in[2];
  const float* b_off1 = (const float*)d_in[3];
  const float* w_off2 = (const float*)d_in[4];
  const float* b_off2 = (const float*)d_in[5];
  const float* w_dcn  = (const float*)d_in[6];
  const float* b_dcn  = (const float*)d_in[7];
  const float* w_sel  = (const float*)d_in[8];
  const float* b_sel  = (const float*)d_in[9];
  const float* w_t1   = (const float*)d_in[10];
  const float* w_t2   = (const float*)d_in[11];
  const float* w_t3   = (const float*)d_in[12];
  const float* w_t4   = (const float*)d_in[13];
  const float* w_t5   = (const float*)d_in[14];

  // workspace layout (bytes); stays within the 176.5 MiB used in prior rounds.
  char* ws = (char*)d_ws;
  float* warp = (float*)(ws);                               // [2,288,HW] f32 = 144 MiB (dead after selconv)
  float* buf1 = (float*)(ws + 150994944);                   // 16 MiB
  float* buf2 = (float*)(ws + 150994944 + 16777216);        // 16 MiB
  int*   idxb = (int*)  (ws + 150994944 + 2*16777216);      // 0.5 MiB
  float* y2   = (float*)(ws);                               // [2,128,HW] f32 = 64 MiB (reuses warp region)
  float* y3   = (float*)(ws + 67108864);                    // 64..128 MiB
  // bf16 weight tables in the 128..144 MiB hole (warp dead, beyond y2/y3)
  unsigned short* wt1hi = (unsigned short*)(ws + 134217728);            // 9216 elems
  unsigned short* wt1lo = wt1hi + 9216;
  unsigned short* wt3hi = (unsigned short*)(ws + 134217728 + 36864);    // 147456 elems
  unsigned short* wt3lo = wt3hi + 147456;
  unsigned short* wt5hi = (unsigned short*)(ws + 134217728 + 36864 + 589824);
  unsigned short* wt5lo = wt5hi + 9216;
  float* out  = (float*)d_out;

  dim3 blk(256);

  // off = lrelu(conv3x3(concat(x,key), w_off1) + b)
  conv3x3_k<64, 8, 1><<<dim3(2 * 4, 4, 16), blk, 0, stream>>>(x, key, 32, w_off1, b_off1, buf1, 32);
  // off = lrelu(conv3x3(off, w_off2) + b)
  conv3x3_k<32, 8, 1><<<dim3(2 * 4, 4, 16), blk, 0, stream>>>(buf1, nullptr, 32, w_off2, b_off2, buf2, 32);
  // warp = conv3x3(concat(key,off), w_dcn) + b   [2,288,H,W]  (exact f32)
  conv3x3_k<64, 8, 0><<<dim3(2 * 36, 4, 16), blk, 0, stream>>>(key, buf2, 32, w_dcn, b_dcn, warp, 288);
  // corr + top-3 per pixel (exact f32)
  corr_topk_k<<<dim3(HW / 256, 2), blk, 0, stream>>>(warp, x, idxb);
  // key_warp -> buf2 (off2 dead)
  selconv_k<<<dim3(8, 32, 2), blk, 0, stream>>>(warp, idxb, w_sel, b_sel, buf2);
  // prep bf16 hi/lo weight tables for the MFMA tail (warp region now dead)
  prep_w_k<<<dim3(36), blk, 0, stream>>>(w_t1, wt1hi, wt1lo, 32, 32);
  prep_w_k<<<dim3(576), blk, 0, stream>>>(w_t3, wt3hi, wt3lo, 128, 128);
  prep_w_k<<<dim3(36), blk, 0, stream>>>(w_t5, wt5hi, wt5lo, 32, 32);
  // tail: t1 (MFMA, gelu out) -> buf1
  conv3x3_mfma_k<32, 32, 2><<<dim3(2, 4, 64), blk, 0, stream>>>(buf2, wt1hi, wt1lo, buf1);
  // t2 1x1 (gelu out) -> y2
  conv1x1_k<32, 16, 2><<<dim3(HW / 1024, 2, 8), blk, 0, stream>>>(buf1, w_t2, y2, 128);
  // t3 (MFMA, gelu out) -> y3
  conv3x3_mfma_k<128, 128, 2><<<dim3(8, 4, 64), blk, 0, stream>>>(y2, wt3hi, wt3lo, y3);
  // t4 1x1 (gelu out) -> buf1
  conv1x1_k<128, 8, 2><<<dim3(HW / 1024, 2, 4), blk, 0, stream>>>(y3, w_t4, buf1, 32);
  // t5 (MFMA, no act) -> out
  conv3x3_mfma_k<32, 32, 0><<<dim3(2, 4, 64), blk, 0, stream>>>(buf1, wt5hi, wt5lo, out);
}

// Round 6
// 848.970 us; speedup vs baseline: 22.0250x; 2.2098x over previous
//
#include <hip/hip_runtime.h>
#include <math.h>

static constexpr int H = 256, W = 256, HW = H * W;

typedef __attribute__((ext_vector_type(8))) _Float16 half8v;  // 8 f16 (4 VGPR)
typedef __attribute__((ext_vector_type(4))) float  float4v;   // MFMA acc

// ---------- activations ----------
__device__ __forceinline__ float gelu_f(float v) {
  return 0.5f * v * (1.0f + erff(v * 0.70710678118654752440f));
}
template<int ACT>
__device__ __forceinline__ float apply_act(float v) {
  if constexpr (ACT == 1) return v >= 0.f ? v : 0.1f * v;   // LeakyReLU(0.1)
  if constexpr (ACT == 2) return gelu_f(v);
  return v;
}

// ---------- weight prep: [OC][CIN][3][3] f32 -> [tap][OC][CIN] f16 hi + scaled lo ----------
// hi = f16(v); lo = f16((v - hi) * 2048)  (scale keeps lo in normal f16 range;
// epilogue divides accQ by 2048). Split-3 product error ~2^-20 relative.
__global__ __launch_bounds__(256)
void prep_w_k(const float* __restrict__ w, _Float16* __restrict__ hi,
              _Float16* __restrict__ lo, int OC, int CIN)
{
  int tid = blockIdx.x * 256 + threadIdx.x;
  if (tid >= OC * CIN * 9) return;
  int ci = tid % CIN; int r = tid / CIN; int oc = r % OC; int tap = r / OC;
  float v = w[((size_t)oc * CIN + ci) * 9 + tap];
  _Float16 h = (_Float16)v;
  hi[tid] = h;
  lo[tid] = (_Float16)((v - (float)h) * 2048.0f);
}

// ---------- 3x3 conv, f16 MFMA split-3 (hh -> accP; h*lo'+lo'*h -> accQ) ----------
// Geometry HW-verified in round 5 (bf16 variant): block=4 waves, tile = 32 oc x
// 64 cols x 4 rows; wave wv owns row y0+wv. MFMA 16x16x32: A row=l&15 (oc),
// k=(l>>4)*8+j; B col=l&15 (px); D col=l&15 (px), row=(l>>4)*4+reg (oc).
// LDS B-tile [6 rows][66 cols][72 halves]: col stride 144B = 9 quad-banks ->
// conflict-free b128 reads/writes. Channel concat: ci<cin0 from in0 (cin0%8==0).
template<int CIN, int OC, int ACT>
__global__ __launch_bounds__(256)
void conv3x3_mfma_k(const float* __restrict__ in0, const float* __restrict__ in1, int cin0,
                    const _Float16* __restrict__ wHi, const _Float16* __restrict__ wLo,
                    const float* __restrict__ bias, float* __restrict__ out)
{
  __shared__ _Float16 sB[6 * 66 * 72];   // 57,024 B

  const int l  = threadIdx.x & 63;
  const int wv = threadIdx.x >> 6;
  const int nOc = OC / 32;
  const int b   = blockIdx.x / nOc;
  const int oc0 = (blockIdx.x % nOc) * 32;
  const int x0  = blockIdx.y * 64;
  const int y0  = blockIdx.z * 4;

  float4v accP[2][4], accQ[2][4];
  #pragma unroll
  for (int of = 0; of < 2; ++of)
    #pragma unroll
    for (int f = 0; f < 4; ++f) {
      accP[of][f] = (float4v){0.f, 0.f, 0.f, 0.f};
      accQ[of][f] = (float4v){0.f, 0.f, 0.f, 0.f};
    }

  const int gx_m  = x0 + l - 1;
  const bool vx_m = (gx_m >= 0 && gx_m < W);
  const int gx_e  = gx_m + 64;                 // cols 64,65 staged by l<2
  const bool vx_e = (l < 2) && (gx_e < W);

  const int k8  = (l >> 4) * 8;
  const int ocl = l & 15;

  #pragma unroll 1
  for (int cc = 0; cc < CIN; cc += 32) {
    __syncthreads();
    // ---- stage: 24 tasks (6 rows x 4 ch-granules of 8), round-robin over waves ----
    #pragma unroll 1
    for (int t = wv; t < 24; t += 4) {
      int r = t >> 2, g = t & 3;
      int gy = y0 + r - 1;
      bool vy = (gy >= 0 && gy < H);
      int gyc = gy < 0 ? 0 : (gy >= H ? H - 1 : gy);
      int ci0 = cc + g * 8;
      const float* base;
      if (ci0 < cin0) base = in0 + (((size_t)b * cin0 + ci0) * H + gyc) * W;
      else            base = in1 + (((size_t)b * (CIN - cin0) + (ci0 - cin0)) * H + gyc) * W;
      half8v h8, q8, h8e, q8e;
      #pragma unroll
      for (int k = 0; k < 8; ++k) {
        float v = (vy && vx_m) ? base[(size_t)k * HW + gx_m] : 0.f;
        _Float16 hh = (_Float16)v;
        h8[k] = hh;
        q8[k] = (_Float16)((v - (float)hh) * 2048.0f);
        float ve = (vy && vx_e) ? base[(size_t)k * HW + gx_e] : 0.f;
        _Float16 he = (_Float16)ve;
        h8e[k] = he;
        q8e[k] = (_Float16)((ve - (float)he) * 2048.0f);
      }
      int basei = (r * 66 + l) * 72 + g * 8;
      *(half8v*)&sB[basei]      = h8;
      *(half8v*)&sB[basei + 32] = q8;
      if (l < 2) {
        int be = (r * 66 + 64 + l) * 72 + g * 8;
        *(half8v*)&sB[be]      = h8e;
        *(half8v*)&sB[be + 32] = q8e;
      }
    }
    __syncthreads();

    #pragma unroll 1
    for (int tap = 0; tap < 9; ++tap) {
      const int dy = tap / 3, dx = tap - 3 * (tap / 3);
      const _Float16* hp = wHi + ((size_t)tap * OC + oc0 + ocl) * CIN + cc + k8;
      const _Float16* lp = wLo + ((size_t)tap * OC + oc0 + ocl) * CIN + cc + k8;
      half8v ah0 = *(const half8v*)hp;
      half8v ah1 = *(const half8v*)(hp + (size_t)16 * CIN);
      half8v aq0 = *(const half8v*)lp;
      half8v aq1 = *(const half8v*)(lp + (size_t)16 * CIN);
      const int brow = ((wv + dy) * 66 + ocl + dx) * 72 + k8;
      #pragma unroll
      for (int f = 0; f < 4; ++f) {
        half8v bh = *(const half8v*)&sB[brow + f * 16 * 72];
        half8v bq = *(const half8v*)&sB[brow + f * 16 * 72 + 32];
        accP[0][f] = __builtin_amdgcn_mfma_f32_16x16x32_f16(ah0, bh, accP[0][f], 0, 0, 0);
        accQ[0][f] = __builtin_amdgcn_mfma_f32_16x16x32_f16(ah0, bq, accQ[0][f], 0, 0, 0);
        accQ[0][f] = __builtin_amdgcn_mfma_f32_16x16x32_f16(aq0, bh, accQ[0][f], 0, 0, 0);
        accP[1][f] = __builtin_amdgcn_mfma_f32_16x16x32_f16(ah1, bh, accP[1][f], 0, 0, 0);
        accQ[1][f] = __builtin_amdgcn_mfma_f32_16x16x32_f16(ah1, bq, accQ[1][f], 0, 0, 0);
        accQ[1][f] = __builtin_amdgcn_mfma_f32_16x16x32_f16(aq1, bh, accQ[1][f], 0, 0, 0);
      }
    }
  }

  // ---- epilogue: D col=l&15 (px), row=(l>>4)*4+reg (oc) ----
  #pragma unroll
  for (int of = 0; of < 2; ++of)
    #pragma unroll
    for (int f = 0; f < 4; ++f)
      #pragma unroll
      for (int r = 0; r < 4; ++r) {
        int oc = oc0 + of * 16 + (l >> 4) * 4 + r;
        float bv = bias ? bias[oc] : 0.f;
        float vv = accP[of][f][r] + accQ[of][f][r] * (1.0f / 2048.0f) + bv;
        out[((size_t)(b * OC + oc) * H + (y0 + wv)) * W + x0 + f * 16 + ocl] = apply_act<ACT>(vv);
      }
}

// ---------- 1x1 conv, f32 (memory-bound) ----------
template<int CIN, int OCPB, int ACT>
__global__ __launch_bounds__(256)
void conv1x1_k(const float* __restrict__ in, const float* __restrict__ w,
               float* __restrict__ out, int ocTotal)
{
  __shared__ __align__(16) float sW[OCPB][CIN];
  const int b   = blockIdx.y;
  const int oc0 = blockIdx.z * OCPB;
  for (int t = threadIdx.x; t < OCPB * CIN; t += 256)
    sW[t / CIN][t % CIN] = w[(size_t)(oc0 + t / CIN) * CIN + (t % CIN)];
  __syncthreads();

  const int p4 = (blockIdx.x * 256 + threadIdx.x) * 4;
  const float* ip = in + (size_t)b * CIN * HW + p4;
  float acc[OCPB][4];
  #pragma unroll
  for (int o = 0; o < OCPB; ++o)
    #pragma unroll
    for (int j = 0; j < 4; ++j) acc[o][j] = 0.f;

  #pragma unroll 2
  for (int ci = 0; ci < CIN; ci += 4) {
    float4 v0 = *(const float4*)(ip + (size_t)(ci + 0) * HW);
    float4 v1 = *(const float4*)(ip + (size_t)(ci + 1) * HW);
    float4 v2 = *(const float4*)(ip + (size_t)(ci + 2) * HW);
    float4 v3 = *(const float4*)(ip + (size_t)(ci + 3) * HW);
    #pragma unroll
    for (int o = 0; o < OCPB; ++o) {
      const float4 wv = *(const float4*)&sW[o][ci];
      acc[o][0] += v0.x * wv.x + v1.x * wv.y + v2.x * wv.z + v3.x * wv.w;
      acc[o][1] += v0.y * wv.x + v1.y * wv.y + v2.y * wv.z + v3.y * wv.w;
      acc[o][2] += v0.z * wv.x + v1.z * wv.y + v2.z * wv.z + v3.z * wv.w;
      acc[o][3] += v0.w * wv.x + v1.w * wv.y + v2.w * wv.z + v3.w * wv.w;
    }
  }
  #pragma unroll
  for (int o = 0; o < OCPB; ++o) {
    float4 v;
    v.x = apply_act<ACT>(acc[o][0]);
    v.y = apply_act<ACT>(acc[o][1]);
    v.z = apply_act<ACT>(acc[o][2]);
    v.w = apply_act<ACT>(acc[o][3]);
    *(float4*)&out[((size_t)b * ocTotal + oc0 + o) * HW + p4] = v;
  }
}

// ---------- corr + top-3 (jax tie-break: lower index wins) ----------
__global__ __launch_bounds__(256)
void corr_topk_k(const float* __restrict__ warp, const float* __restrict__ x,
                 int* __restrict__ idxo)
{
  const int p = blockIdx.x * 256 + threadIdx.x;
  const int b = blockIdx.y;
  float corr[9];
  #pragma unroll
  for (int o = 0; o < 9; ++o) corr[o] = 0.f;
  #pragma unroll 2
  for (int c = 0; c < 32; ++c) {
    float xv = x[((size_t)b * 32 + c) * HW + p];
    const float* wp = warp + ((size_t)b * 288 + (size_t)c * 9) * HW + p;
    #pragma unroll
    for (int o = 0; o < 9; ++o) corr[o] += wp[(size_t)o * HW] * xv;
  }
  unsigned mask = 0;
  int packed = 0;
  #pragma unroll
  for (int t = 0; t < 3; ++t) {
    float best = -INFINITY; int bi = 0;
    #pragma unroll
    for (int o = 0; o < 9; ++o) {
      bool take = (((mask >> o) & 1u) == 0u) && (corr[o] > best);
      best = take ? corr[o] : best;
      bi   = take ? o       : bi;
    }
    mask   |= 1u << bi;
    packed |= bi << (4 * t);
  }
  idxo[(size_t)b * HW + p] = packed;
}

// ---------- gather selected warps + 3x3 conv with w_sel ----------
__global__ __launch_bounds__(256)
void selconv_k(const float* __restrict__ warp, const int* __restrict__ idxp,
               const float* __restrict__ wsel, const float* __restrict__ bsel,
               float* __restrict__ out)
{
  const int tx = threadIdx.x & 31, ty = threadIdx.x >> 5;
  const int px = blockIdx.x * 32 + tx;
  const int py = blockIdx.y * 8 + ty;
  const int b  = blockIdx.z;

  int  nidx[9];
  bool nval[9];
  int  qoff[9];
  #pragma unroll
  for (int kh = 0; kh < 3; ++kh)
    #pragma unroll
    for (int kw = 0; kw < 3; ++kw) {
      int k = kh * 3 + kw;
      int qy = py + kh - 1, qx = px + kw - 1;
      nval[k] = (qy >= 0 && qy < H && qx >= 0 && qx < W);
      qoff[k] = qy * W + qx;
      nidx[k] = nval[k] ? idxp[(size_t)b * HW + qoff[k]] : 0;
    }

  float ws27[27];
  #pragma unroll
  for (int i = 0; i < 27; ++i) ws27[i] = wsel[i];
  const float bs = bsel[0];

  #pragma unroll 1
  for (int c = 0; c < 32; ++c) {
    float acc = bs;
    const float* wb = warp + ((size_t)b * 288 + (size_t)c * 9) * HW;
    #pragma unroll
    for (int k = 0; k < 9; ++k) {
      if (nval[k]) {
        int pk = nidx[k];
        #pragma unroll
        for (int t = 0; t < 3; ++t) {
          int o = (pk >> (4 * t)) & 15;
          acc += ws27[t * 9 + k] * wb[(size_t)o * HW + qoff[k]];
        }
      }
    }
    out[((size_t)b * 32 + c) * HW + (size_t)py * W + px] = acc;
  }
}

// ---------- launch ----------
extern "C" void kernel_launch(void* const* d_in, const int* in_sizes, int n_in,
                              void* d_out, int out_size, void* d_ws, size_t ws_size,
                              hipStream_t stream) {
  const float* x      = (const float*)d_in[0];
  const float* key    = (const float*)d_in[1];
  const float* w_off1 = (const float*)d_in[2];
  const float* b_off1 = (const float*)d_in[3];
  const float* w_off2 = (const float*)d_in[4];
  const float* b_off2 = (const float*)d_in[5];
  const float* w_dcn  = (const float*)d_in[6];
  const float* b_dcn  = (const float*)d_in[7];
  const float* w_sel  = (const float*)d_in[8];
  const float* b_sel  = (const float*)d_in[9];
  const float* w_t1   = (const float*)d_in[10];
  const float* w_t2   = (const float*)d_in[11];
  const float* w_t3   = (const float*)d_in[12];
  const float* w_t4   = (const float*)d_in[13];
  const float* w_t5   = (const float*)d_in[14];

  // workspace layout (bytes); peak ~177.3 MiB
  char* ws = (char*)d_ws;
  float* warp = (float*)(ws);                               // [2,288,HW] f32 = 144 MiB
  float* buf1 = (float*)(ws + 150994944);                   // 16 MiB
  float* buf2 = (float*)(ws + 150994944 + 16777216);        // 16 MiB
  int*   idxb = (int*)  (ws + 184549376);                   // 0.5 MiB
  // phase-1 f16 weight tables (live until dcn finishes): appended after idx
  _Float16* o1Hi = (_Float16*)(ws + 185073664);             // 18432 elems
  _Float16* o1Lo = o1Hi + 18432;
  _Float16* o2Hi = o1Lo + 18432;                            // 9216
  _Float16* o2Lo = o2Hi + 9216;
  _Float16* dcHi = o2Lo + 9216;                             // 165888
  _Float16* dcLo = dcHi + 165888;
  // tail reuse of warp region
  float* y2 = (float*)(ws);                                 // 64 MiB
  float* y3 = (float*)(ws + 67108864);                      // 64 MiB (ends at 128 MiB)
  // phase-2 tables in dead warp region [128 MiB, 144 MiB), written after selconv
  _Float16* t1Hi = (_Float16*)(ws + 134217728);             // 9216
  _Float16* t1Lo = t1Hi + 9216;
  _Float16* t3Hi = t1Lo + 9216;                             // 147456
  _Float16* t3Lo = t3Hi + 147456;
  _Float16* t5Hi = t3Lo + 147456;                           // 9216
  _Float16* t5Lo = t5Hi + 9216;
  float* out = (float*)d_out;

  dim3 blk(256);

  // phase-1 weight prep
  prep_w_k<<<dim3(72),  blk, 0, stream>>>(w_off1, o1Hi, o1Lo, 32, 64);
  prep_w_k<<<dim3(36),  blk, 0, stream>>>(w_off2, o2Hi, o2Lo, 32, 32);
  prep_w_k<<<dim3(648), blk, 0, stream>>>(w_dcn,  dcHi, dcLo, 288, 64);

  // off = lrelu(conv3x3(concat(x,key), w_off1) + b)
  conv3x3_mfma_k<64, 32, 1><<<dim3(2, 4, 64), blk, 0, stream>>>(x, key, 32, o1Hi, o1Lo, b_off1, buf1);
  // off = lrelu(conv3x3(off, w_off2) + b)
  conv3x3_mfma_k<32, 32, 1><<<dim3(2, 4, 64), blk, 0, stream>>>(buf1, nullptr, 32, o2Hi, o2Lo, b_off2, buf2);
  // warp = conv3x3(concat(key,off), w_dcn) + b   [2,288,H,W]
  conv3x3_mfma_k<64, 288, 0><<<dim3(2 * 9, 4, 64), blk, 0, stream>>>(key, buf2, 32, dcHi, dcLo, b_dcn, warp);
  // corr + top-3 per pixel (f32 from stored warp)
  corr_topk_k<<<dim3(HW / 256, 2), blk, 0, stream>>>(warp, x, idxb);
  // key_warp -> buf2 (off dead)
  selconv_k<<<dim3(8, 32, 2), blk, 0, stream>>>(warp, idxb, w_sel, b_sel, buf2);

  // phase-2 weight prep (warp region now dead)
  prep_w_k<<<dim3(36),  blk, 0, stream>>>(w_t1, t1Hi, t1Lo, 32, 32);
  prep_w_k<<<dim3(576), blk, 0, stream>>>(w_t3, t3Hi, t3Lo, 128, 128);
  prep_w_k<<<dim3(36),  blk, 0, stream>>>(w_t5, t5Hi, t5Lo, 32, 32);

  // tail
  conv3x3_mfma_k<32, 32, 2><<<dim3(2, 4, 64), blk, 0, stream>>>(buf2, nullptr, 32, t1Hi, t1Lo, nullptr, buf1);
  conv1x1_k<32, 16, 2><<<dim3(HW / 1024, 2, 8), blk, 0, stream>>>(buf1, w_t2, y2, 128);
  conv3x3_mfma_k<128, 128, 2><<<dim3(2 * 4, 4, 64), blk, 0, stream>>>(y2, nullptr, 128, t3Hi, t3Lo, nullptr, y3);
  conv1x1_k<128, 8, 2><<<dim3(HW / 1024, 2, 4), blk, 0, stream>>>(y3, w_t4, buf1, 32);
  conv3x3_mfma_k<32, 32, 0><<<dim3(2, 4, 64), blk, 0, stream>>>(buf1, nullptr, 32, t5Hi, t5Lo, nullptr, out);
}